// Round 13
// baseline (234.563 us; speedup 1.0000x reference)
//
#include <hip/hip_runtime.h>
#include <stdint.h>

// B=4 N=32 L=S=256 H=8 E=D=64
// grid = B*N*H = 1024 blocks, 1024 threads (16 waves), one (b,n,h) per block.
// R12: BARRIER-FREE main loop. V staged once (transposed+swizzled, 32KB,
// R6-verified) behind a single __syncthreads; K fragments loaded per-wave
// DIRECTLY from global (L2-resident: 16KB/interval, all 16 waves share);
// waves run their 4 intervals fully desynchronized so load/compute phases
// interleave across the CU (fixes the lockstep burst-then-idle pattern that
// capped in-flight bytes). Body otherwise = R11 (verified): 64-col
// intervals, one online-softmax update per interval, swapped-MFMA,
// in-register P redistribution, prior depth-1 pipeline, nontemporal
// prior/score streams.

typedef __attribute__((ext_vector_type(8))) short bfrag;   // 8 bf16 (4 VGPRs)
typedef __attribute__((ext_vector_type(4))) float f32x4;
typedef __attribute__((ext_vector_type(4))) int i32x4;

__device__ __forceinline__ uint32_t f2bf(float f) {
  uint32_t u = __builtin_bit_cast(uint32_t, f);
  return (u + 0x7FFFu + ((u >> 16) & 1u)) >> 16;   // RNE f32->bf16 (finite data)
}
__device__ __forceinline__ uint32_t pk(float a, float b) {
  return f2bf(a) | (f2bf(b) << 16);
}

#define MFMA(a, b, c) __builtin_amdgcn_mfma_f32_16x16x32_bf16((a), (b), (c), 0, 0, 0)

__global__ __launch_bounds__(1024, 2) void attn_kernel(
    const float* __restrict__ Qg, const float* __restrict__ Kg,
    const float* __restrict__ Vg, const float* __restrict__ Pg,
    float* __restrict__ Sc, float* __restrict__ Ov)
{
  // V: [64 d][256 s] bf16, 512B rows, byte ^= (d&7)<<4   (32768 B)
  __shared__ char Vt[64 * 512];

  const int bnh = blockIdx.x;
  const int bn = bnh >> 3, h = bnh & 7;
  const int t = threadIdx.x;
  const int lane = t & 63;
  const int wave = t >> 6;    // 0..15
  const int ql = lane & 15;   // q within 16-tile (MFMA col)
  const int g  = lane >> 4;   // 4-group (MFMA row group / k-slice)
  // magic-square q-tile permutation (per-SIMD PV balance)
  const int qt = (int)((0x783C96D25A1EB4F0ull >> (wave * 4)) & 15);
  const int q = qt * 16 + ql;
  const int pvmax = qt >> 2;        // causal gate in 64-col intervals
  const int swz = (ql & 7) << 4;    // lane-constant V read swizzle
  const float temp = 0.125f;        // 1/sqrt(64)

  // ---- stage V transposed once as bf16 [d][s] (R6-verified pattern) ----
  {
    const int d = t & 63, sg = t >> 6;           // sg 0..15
    const float* vp = Vg + (size_t)bn * 131072 + h * 64 + d;
#pragma unroll
    for (int it = 0; it < 4; ++it) {
      const int sv = it * 64 + sg * 4;
      const float v0 = vp[(size_t)(sv + 0) * 512];
      const float v1 = vp[(size_t)(sv + 1) * 512];
      const float v2 = vp[(size_t)(sv + 2) * 512];
      const float v3 = vp[(size_t)(sv + 3) * 512];
      uint2 vv;
      vv.x = pk(v0, v1);
      vv.y = pk(v2, v3);
      *(uint2*)(Vt + ((d * 512 + sv * 2) ^ ((d & 7) << 4))) = vv;
    }
  }

  // ---- Q fragments direct from global (B-operand of swapped QK) ----
  bfrag qf[2];
#pragma unroll
  for (int ks = 0; ks < 2; ++ks) {
    const float* qp = Qg + (size_t)bn * 131072 + (size_t)q * 512 + h * 64 + ks * 32 + g * 8;
    const f32x4 qa = *(const f32x4*)qp;
    const f32x4 qb = *(const f32x4*)(qp + 4);
    union { i32x4 i; bfrag b; } u;
    u.i = i32x4{(int)pk(qa.x, qa.y), (int)pk(qa.z, qa.w),
                (int)pk(qb.x, qb.y), (int)pk(qb.z, qb.w)};
    qf[ks] = u.b;
  }

  __syncthreads();   // the ONLY block-wide sync

  f32x4 O[4];
#pragma unroll
  for (int ds = 0; ds < 4; ++ds) O[ds] = f32x4{0.f, 0.f, 0.f, 0.f};
  float m = -1e30f, lsum = 0.f;

  const size_t scb = (size_t)bnh << 16;
  const float* prp = Pg + scb + (size_t)q * 256 + 4 * g;   // + 16*j + 64*it
  float* scp = Sc + scb + (size_t)q * 256 + 4 * g;
  const float* kgb = Kg + (size_t)bn * 131072 + h * 64 + g * 8;   // + row*512 (+32 for ks=1)

  // prior pipeline: 4 x f32x4 for the 64-col interval (constant indices only)
  f32x4 pr[4];
#pragma unroll
  for (int j = 0; j < 4; ++j)
    pr[j] = __builtin_nontemporal_load((const f32x4*)(prp + 16 * j));

#pragma unroll 1
  for (int it = 0; it < 4; ++it) {
    const int s0 = it * 64;
    // QK^T swapped over 64 cols: K fragments straight from global (L2-hot).
    f32x4 acc[2][2];
#pragma unroll
    for (int sub = 0; sub < 2; ++sub)
#pragma unroll
      for (int ss = 0; ss < 2; ++ss) {
        const int srow = s0 + sub * 32 + 16 * ss + ql;
        const float* kp = kgb + (size_t)srow * 512;
        const f32x4 ka = *(const f32x4*)kp;          // e = g*8 .. +3   (ks=0)
        const f32x4 kb = *(const f32x4*)(kp + 4);    // e = g*8+4 .. +7
        const f32x4 kc = *(const f32x4*)(kp + 32);   // ks=1 half
        const f32x4 kd = *(const f32x4*)(kp + 36);
        union { i32x4 i; bfrag b; } u0, u1;
        u0.i = i32x4{(int)pk(ka.x, ka.y), (int)pk(ka.z, ka.w),
                     (int)pk(kb.x, kb.y), (int)pk(kb.z, kb.w)};
        u1.i = i32x4{(int)pk(kc.x, kc.y), (int)pk(kc.z, kc.w),
                     (int)pk(kd.x, kd.y), (int)pk(kd.z, kd.w)};
        f32x4 a = f32x4{0.f, 0.f, 0.f, 0.f};
        a = MFMA(u0.b, qf[0], a);
        a = MFMA(u1.b, qf[1], a);
        const int sb = s0 + sub * 32 + 16 * ss + 4 * g;
#pragma unroll
        for (int r = 0; r < 4; ++r)
          a[r] = (sb + r <= q) ? a[r] : a[r] - 1e9f;   // analytic causal mask
        acc[sub][ss] = a + pr[sub * 2 + ss];           // scores = QK+mask+prior
      }

    // prior consumed -> issue next interval's loads NOW
    if (it < 3) {
#pragma unroll
      for (int j = 0; j < 4; ++j)
        pr[j] = __builtin_nontemporal_load(
            (const f32x4*)(prp + (it + 1) * 64 + 16 * j));
    }

    // scores out (4 x dwordx4)
    __builtin_nontemporal_store(acc[0][0], (f32x4*)(scp + s0));
    __builtin_nontemporal_store(acc[0][1], (f32x4*)(scp + s0 + 16));
    __builtin_nontemporal_store(acc[1][0], (f32x4*)(scp + s0 + 32));
    __builtin_nontemporal_store(acc[1][1], (f32x4*)(scp + s0 + 48));

    if (it <= pvmax) {   // ONE online-softmax update per 64-col interval
      float tm = -1e30f;
#pragma unroll
      for (int sub = 0; sub < 2; ++sub)
#pragma unroll
        for (int ss = 0; ss < 2; ++ss)
#pragma unroll
          for (int r = 0; r < 4; ++r) tm = fmaxf(tm, acc[sub][ss][r]);
      tm = fmaxf(tm, __shfl_xor(tm, 16));
      tm = fmaxf(tm, __shfl_xor(tm, 32));
      tm *= temp;
      const float mnew = fmaxf(m, tm);
      const float fct = __expf(m - mnew);
      m = mnew;
      float pv[16];
#pragma unroll
      for (int sub = 0; sub < 2; ++sub)
#pragma unroll
        for (int ss = 0; ss < 2; ++ss)
#pragma unroll
          for (int r = 0; r < 4; ++r)
            pv[sub * 8 + ss * 4 + r] = __expf(fmaf(temp, acc[sub][ss][r], -mnew));
      float ts = 0.f;
#pragma unroll
      for (int j = 0; j < 16; ++j) ts += pv[j];
      ts += __shfl_xor(ts, 16);
      ts += __shfl_xor(ts, 32);
      lsum = lsum * fct + ts;
#pragma unroll
      for (int ds = 0; ds < 4; ++ds) O[ds] *= fct;

      // per 32-col sub-tile: pack P to bf16, redistribute to PV B-fragment
      // layout (lane (ql,g) needs s_loc = 8g..8g+7), then PV MFMA.
#pragma unroll
      for (int sub = 0; sub < 2; ++sub) {
        const int w0x = (int)pk(pv[sub * 8 + 0], pv[sub * 8 + 1]);
        const int w0y = (int)pk(pv[sub * 8 + 2], pv[sub * 8 + 3]);
        const int w1x = (int)pk(pv[sub * 8 + 4], pv[sub * 8 + 5]);
        const int w1y = (int)pk(pv[sub * 8 + 6], pv[sub * 8 + 7]);
        const int srcA = ((g & 1) << 5) + ql;     // lane of g' = (2g)&3
        const int a0 = __shfl(w0x, srcA),      a1 = __shfl(w1x, srcA);
        const int b0 = __shfl(w0y, srcA),      b1 = __shfl(w1y, srcA);
        const int c0 = __shfl(w0x, srcA + 16), c1 = __shfl(w1x, srcA + 16);
        const int d0 = __shfl(w0y, srcA + 16), d1 = __shfl(w1y, srcA + 16);
        union { i32x4 i; bfrag b; } pu;
        pu.i = i32x4{g < 2 ? a0 : a1, g < 2 ? b0 : b1,
                     g < 2 ? c0 : c1, g < 2 ? d0 : d1};
#pragma unroll
        for (int ds = 0; ds < 4; ++ds) {
          bfrag vf = *(const bfrag*)(Vt +
              (((16 * ds + ql) * 512 + (s0 + sub * 32) * 2 + g * 16) ^ swz));
          O[ds] = MFMA(vf, pu.b, O[ds]);
        }
      }
    }
  }

  // epilogue: O /= l, store dwordx4 (d-consecutive regs)
  {
    const float inv = 1.f / lsum;
    float* op = Ov + (size_t)bn * 131072 + (size_t)q * 512 + h * 64 + 4 * g;
#pragma unroll
    for (int ds = 0; ds < 4; ++ds) {
      f32x4 o = O[ds] * inv;
      *(f32x4*)(op + 16 * ds) = o;
    }
  }
}

extern "C" void kernel_launch(void* const* d_in, const int* in_sizes, int n_in,
                              void* d_out, int out_size, void* d_ws, size_t ws_size,
                              hipStream_t stream) {
  const float* Qg = (const float*)d_in[0];   // queries  [B,N,L,H,E]
  const float* Kg = (const float*)d_in[1];   // keys     [B,N,S,H,E]
  const float* Vg = (const float*)d_in[2];   // values   [B,N,S,H,D]
  const float* Pg = (const float*)d_in[4];   // attn_scores [B,N,H,L,S]
  float* Sc = (float*)d_out;                            // scores out
  float* Ov = Sc + (size_t)4 * 32 * 8 * 256 * 256;      // V out
  attn_kernel<<<dim3(1024), dim3(1024), 0, stream>>>(Qg, Kg, Vg, Pg, Sc, Ov);
}

// Round 14
// 150.246 us; speedup vs baseline: 1.5612x; 1.5612x over previous
//
#include <hip/hip_runtime.h>
#include <stdint.h>

// B=4 N=32 L=S=256 H=8 E=D=64
// R13: PERSISTENT grid — 256 blocks (1/CU) x 1024 threads, each block
// processes 4 bnh sequentially (bnh = bi*256 + blockIdx.x). Removes 3 of 4
// block-generation drains + launch gaps (the only surviving counter-backed
// theory for the 151-158us plateau). Body per bnh = R9 verified structure:
// per-tile double-buffered 4KB K/V slices, raw lgkmcnt-only barriers,
// named staging regs, swapped-MFMA, in-register P redistribution, depth-1
// prior prefetch (loop-carried scalars), magic-square q-tile permutation.

typedef __attribute__((ext_vector_type(8))) short bfrag;   // 8 bf16 (4 VGPRs)
typedef __attribute__((ext_vector_type(4))) float f32x4;
typedef __attribute__((ext_vector_type(2))) float f32x2;
typedef __attribute__((ext_vector_type(4))) int i32x4;

__device__ __forceinline__ uint32_t f2bf(float f) {
  uint32_t u = __builtin_bit_cast(uint32_t, f);
  return (u + 0x7FFFu + ((u >> 16) & 1u)) >> 16;   // RNE f32->bf16 (finite data)
}
__device__ __forceinline__ uint32_t pk(float a, float b) {
  return f2bf(a) | (f2bf(b) << 16);
}

#define MFMA(a, b, c) __builtin_amdgcn_mfma_f32_16x16x32_bf16((a), (b), (c), 0, 0, 0)

__global__ __launch_bounds__(1024, 2) void attn_kernel(
    const float* __restrict__ Qg, const float* __restrict__ Kg,
    const float* __restrict__ Vg, const float* __restrict__ Pg,
    float* __restrict__ Sc, float* __restrict__ Ov)
{
  // K slice: [32 s][64 e] bf16, 128B rows, byte ^= (s&7)<<4   (4096 B x2)
  // V slice: [64 d][32 s] bf16, 64B rows,  byte ^= (d&3)<<4   (4096 B x2)
  __shared__ char Kb[2][4096];
  __shared__ char Vb[2][4096];

  const int t = threadIdx.x;
  const int lane = t & 63;
  const int wave = t >> 6;    // 0..15
  const int ql = lane & 15;   // q within 16-tile (MFMA col)
  const int g  = lane >> 4;   // 4-group (MFMA row group / k-slice)
  // magic-square q-tile permutation (per-SIMD PV balance)
  const int qt = (int)((0x783C96D25A1EB4F0ull >> (wave * 4)) & 15);
  const int q = qt * 16 + ql;
  const int pvmax = qt >> 1;        // causal: PV only for st <= pvmax
  const int swzk = (ql & 7) << 4;   // K slice read swizzle (lane-constant)
  const int swzv = (ql & 3) << 4;   // V slice read swizzle
  const float temp = 0.125f;        // 1/sqrt(64)

  // ---- staging roles (thread-constant) ----
  const int kr_ = t >> 5;          // K slice row 0..31
  const int kc_ = t & 31;          // K f32-pair col (floats 2*kc_)
  const int vd_ = t & 63;          // V: d
  const int vw_ = t >> 6;          // V: s-pair index 0..15
  const int kwoff = (kr_ * 128 + kc_ * 4) ^ ((kr_ & 7) << 4);
  const int vwoff = (vd_ * 64 + vw_ * 4) ^ ((vd_ & 3) << 4);

#pragma unroll 1
  for (int bi = 0; bi < 4; ++bi) {
    const int bnh = (bi << 8) + blockIdx.x;
    const int bn = bnh >> 3, h = bnh & 7;

    const float* kgp = Kg + (size_t)bn * 131072 + h * 64 + (size_t)kr_ * 512 + 2 * kc_;
    const float* vgp = Vg + (size_t)bn * 131072 + h * 64 + (size_t)(2 * vw_) * 512 + vd_;

    // ---- prologue: stage tile 0 into buf 0, then issue tile-1 loads ----
    // (previous bnh's final barrier guarantees all reads of both bufs done)
    f32x2 kreg = *(const f32x2*)kgp;
    float vreg0 = vgp[0], vreg1 = vgp[512];
    *(uint32_t*)(&Kb[0][0] + kwoff) = pk(kreg[0], kreg[1]);
    *(uint32_t*)(&Vb[0][0] + vwoff) = pk(vreg0, vreg1);
    kreg = *(const f32x2*)(kgp + 16384);
    vreg0 = vgp[16384];
    vreg1 = vgp[16384 + 512];

    // ---- Q fragments direct from global (B-operand of swapped QK) ----
    bfrag qf[2];
#pragma unroll
    for (int ks = 0; ks < 2; ++ks) {
      const float* qp = Qg + (size_t)bn * 131072 + (size_t)q * 512 + h * 64 + ks * 32 + g * 8;
      const f32x4 qa = *(const f32x4*)qp;
      const f32x4 qb = *(const f32x4*)(qp + 4);
      union { i32x4 i; bfrag b; } u;
      u.i = i32x4{(int)pk(qa.x, qa.y), (int)pk(qa.z, qa.w),
                  (int)pk(qb.x, qb.y), (int)pk(qb.z, qb.w)};
      qf[ks] = u.b;
    }

    f32x4 O[4];
#pragma unroll
    for (int ds = 0; ds < 4; ++ds) O[ds] = f32x4{0.f, 0.f, 0.f, 0.f};
    float m = -1e30f, lsum = 0.f;

    const size_t scb = (size_t)bnh << 16;
    const float* prp = Pg + scb + (size_t)q * 256 + 4 * g;   // + 16*ss + 32*st
    float* scp = Sc + scb + (size_t)q * 256 + 4 * g;

    // prior pipeline: loop-carried scalars, loaded for tile 0 here
    f32x4 pr0 = __builtin_nontemporal_load((const f32x4*)(prp));
    f32x4 pr1 = __builtin_nontemporal_load((const f32x4*)(prp + 16));

    asm volatile("s_waitcnt lgkmcnt(0)" ::: "memory");
    __builtin_amdgcn_s_barrier();

#pragma unroll 1
    for (int st = 0; st < 8; ++st) {
      const int s0 = st * 32;
      const int p = (st & 1) << 12;
      bfrag kf[2][2];
#pragma unroll
      for (int ss = 0; ss < 2; ++ss)
#pragma unroll
        for (int ks = 0; ks < 2; ++ks)
          kf[ss][ks] = *(const bfrag*)(&Kb[0][0] + p +
              (((16 * ss + ql) * 128 + ks * 64 + g * 16) ^ swzk));

      // QK^T swapped -> D[s16][q16]; regs are s-consecutive at fixed q
      f32x4 acc[2];
#pragma unroll
      for (int ss = 0; ss < 2; ++ss) {
        f32x4 a = f32x4{0.f, 0.f, 0.f, 0.f};
        a = MFMA(kf[ss][0], qf[0], a);
        a = MFMA(kf[ss][1], qf[1], a);
        const int sb = s0 + 16 * ss + 4 * g;
        // analytic causal mask: s<=q allowed, else -1e9 (matches input mask)
#pragma unroll
        for (int r = 0; r < 4; ++r)
          a[r] = (sb + r <= q) ? a[r] : a[r] - 1e9f;
        acc[ss] = a + (ss == 0 ? pr0 : pr1);   // scores = QK + mask + prior
      }

      // prior consumed -> issue next tile's loads NOW
      if (st < 7) {
        pr0 = __builtin_nontemporal_load((const f32x4*)(prp + (st + 1) * 32));
        pr1 = __builtin_nontemporal_load((const f32x4*)(prp + (st + 1) * 32 + 16));
      }

      // scores out
      __builtin_nontemporal_store(acc[0], (f32x4*)(scp + s0));
      __builtin_nontemporal_store(acc[1], (f32x4*)(scp + s0 + 16));

      if (st <= pvmax) {  // tiles fully in the causal-masked region skip softmax/PV
        float tm = fmaxf(fmaxf(fmaxf(acc[0][0], acc[0][1]), fmaxf(acc[0][2], acc[0][3])),
                         fmaxf(fmaxf(acc[1][0], acc[1][1]), fmaxf(acc[1][2], acc[1][3])));
        tm = fmaxf(tm, __shfl_xor(tm, 16));
        tm = fmaxf(tm, __shfl_xor(tm, 32));
        tm *= temp;
        const float mnew = fmaxf(m, tm);
        const float fct = __expf(m - mnew);
        m = mnew;
        float pv[8];
#pragma unroll
        for (int ss = 0; ss < 2; ++ss)
#pragma unroll
          for (int r = 0; r < 4; ++r)
            pv[ss * 4 + r] = __expf(fmaf(temp, acc[ss][r], -mnew));
        float ts = (pv[0] + pv[1]) + (pv[2] + pv[3]) + (pv[4] + pv[5]) + (pv[6] + pv[7]);
        ts += __shfl_xor(ts, 16);
        ts += __shfl_xor(ts, 32);
        lsum = lsum * fct + ts;
#pragma unroll
        for (int ds = 0; ds < 4; ++ds) O[ds] *= fct;

        // pack P to bf16 and redistribute in-register to the PV B-fragment
        // layout (lane (ql,g) needs s = s0+8g..8g+7). Held: w0 = s 4g..4g+3,
        // w1 = s 16+4g..+3. Sources: lanes g'={2g&3,(2g+1)&3}, pick by g<2.
        const int w0x = (int)pk(pv[0], pv[1]), w0y = (int)pk(pv[2], pv[3]);
        const int w1x = (int)pk(pv[4], pv[5]), w1y = (int)pk(pv[6], pv[7]);
        const int srcA = ((g & 1) << 5) + ql;       // lane of g' = (2g)&3
        const int a0 = __shfl(w0x, srcA),      a1 = __shfl(w1x, srcA);
        const int b0 = __shfl(w0y, srcA),      b1 = __shfl(w1y, srcA);
        const int c0 = __shfl(w0x, srcA + 16), c1 = __shfl(w1x, srcA + 16);
        const int d0 = __shfl(w0y, srcA + 16), d1 = __shfl(w1y, srcA + 16);
        union { i32x4 i; bfrag b; } pu;
        pu.i = i32x4{g < 2 ? a0 : a1, g < 2 ? b0 : b1,
                     g < 2 ? c0 : c1, g < 2 ? d0 : d1};

        // PV swapped: O^T[d][q] += V^T[d x s32] * P^T[s32 x q16]
        bfrag vf[4];
#pragma unroll
        for (int ds = 0; ds < 4; ++ds)
          vf[ds] = *(const bfrag*)(&Vb[0][0] + p +
              (((16 * ds + ql) * 64 + g * 16) ^ swzv));
#pragma unroll
        for (int ds = 0; ds < 4; ++ds) O[ds] = MFMA(vf[ds], pu.b, O[ds]);
      }

      // write staged K/V regs (tile st+1) into the opposite buffer, then
      // issue tile st+2 loads into the same (now free) regs
      if (st < 7) {
        const int p1 = ((st + 1) & 1) << 12;
        *(uint32_t*)(&Kb[0][0] + p1 + kwoff) = pk(kreg[0], kreg[1]);
        *(uint32_t*)(&Vb[0][0] + p1 + vwoff) = pk(vreg0, vreg1);
        if (st < 6) {
          kreg = *(const f32x2*)(kgp + (size_t)(st + 2) * 16384);
          vreg0 = vgp[(st + 2) * 16384];
          vreg1 = vgp[(st + 2) * 16384 + 512];
        }
      }
      asm volatile("s_waitcnt lgkmcnt(0)" ::: "memory");
      __builtin_amdgcn_s_barrier();
    }

    // epilogue: O /= l, store dwordx4 (d-consecutive regs)
    {
      const float inv = 1.f / lsum;
      float* op = Ov + (size_t)bn * 131072 + (size_t)q * 512 + h * 64 + 4 * g;
#pragma unroll
      for (int ds = 0; ds < 4; ++ds) {
        f32x4 o = O[ds] * inv;
        *(f32x4*)(op + 16 * ds) = o;
      }
    }
  }
}

extern "C" void kernel_launch(void* const* d_in, const int* in_sizes, int n_in,
                              void* d_out, int out_size, void* d_ws, size_t ws_size,
                              hipStream_t stream) {
  const float* Qg = (const float*)d_in[0];   // queries  [B,N,L,H,E]
  const float* Kg = (const float*)d_in[1];   // keys     [B,N,S,H,E]
  const float* Vg = (const float*)d_in[2];   // values   [B,N,S,H,D]
  const float* Pg = (const float*)d_in[4];   // attn_scores [B,N,H,L,S]
  float* Sc = (float*)d_out;                            // scores out
  float* Ov = Sc + (size_t)4 * 32 * 8 * 256 * 256;      // V out
  attn_kernel<<<dim3(256), dim3(1024), 0, stream>>>(Qg, Kg, Vg, Pg, Sc, Ov);
}